// Round 1
// baseline (308.250 us; speedup 1.0000x reference)
//
#include <hip/hip_runtime.h>
#include <hip/hip_bf16.h>

// Problem constants (CrossEncoder): B=4, QT=1024, N=2048, E=512, H=8, Dh=64
#define B_  4
#define QT_ 1024
#define N_  2048
#define E_  512
#define H_  8
#define DH_ 64

typedef float  f32x4  __attribute__((ext_vector_type(4)));
typedef __bf16 bf16x8 __attribute__((ext_vector_type(8)));
typedef unsigned short u16;
typedef u16 u16x8 __attribute__((ext_vector_type(8)));

// round-to-nearest-even f32 -> bf16
static __device__ __forceinline__ u16 f2bf(float f) {
    unsigned u = __builtin_bit_cast(unsigned, f);
    return (u16)((u + 0x7fffu + ((u >> 16) & 1u)) >> 16);
}

static __device__ __forceinline__ bf16x8 ldbf8(const u16* p) {
    uint4 v = *reinterpret_cast<const uint4*>(p);
    return __builtin_bit_cast(bf16x8, v);
}

#define MFMA16(a, b, c) __builtin_amdgcn_mfma_f32_16x16x32_bf16((a), (b), (c), 0, 0, 0)

// -------------------- f32 -> bf16 convert (vectorized) --------------------
__global__ __launch_bounds__(256) void cvt_f32_bf16(const float* __restrict__ s,
                                                    u16* __restrict__ d, int n4) {
    int i = blockIdx.x * 256 + threadIdx.x;
    if (i >= n4) return;
    float4 v = reinterpret_cast<const float4*>(s)[i];
    ushort4 o;
    o.x = f2bf(v.x); o.y = f2bf(v.y); o.z = f2bf(v.z); o.w = f2bf(v.w);
    reinterpret_cast<ushort4*>(d)[i] = o;
}

// -------------------- weight transpose + convert: Wt[n][k] = bf16(W[k][n]) --------------------
__global__ __launch_bounds__(256) void w_transpose(const float* __restrict__ W,
                                                   u16* __restrict__ Wt) {
    __shared__ float t[64][65];
    int k0 = blockIdx.x * 64, n0 = blockIdx.y * 64;
    int tid = threadIdx.x;
#pragma unroll
    for (int i = 0; i < 16; i++) {
        int idx = tid + i * 256, r = idx >> 6, c = idx & 63;
        t[r][c] = W[(k0 + r) * E_ + n0 + c];
    }
    __syncthreads();
#pragma unroll
    for (int i = 0; i < 16; i++) {
        int idx = tid + i * 256, r = idx >> 6, c = idx & 63;
        Wt[(n0 + r) * E_ + k0 + c] = f2bf(t[c][r]);
    }
}

// -------------------- RoPE table: tab[row*16 + k] = (cos, sin)(pos[row] * 10000^(-k/32)) ----
// NOTE reference quirk: cos/sin are repeat(2)'d THEN sliced [:32], so pair i uses freq
// index i//2 = d>>2 -> only 16 distinct frequencies.
__global__ __launch_bounds__(256) void rope_table(const int* __restrict__ pos,
                                                  float2* __restrict__ tab, int rows) {
    int i = blockIdx.x * 256 + threadIdx.x;
    if (i >= rows * 16) return;
    int k = i & 15, row = i >> 4;
    float fr = exp2f((float)k * -0.41524101186092028f);  // log2(10000)/32
    float ang = (float)pos[row] * fr;
    float sn, cs;
    sincosf(ang, &sn, &cs);
    tab[i] = make_float2(cs, sn);
}

// -------------------- projection GEMM: out[M,512] = X[M,512] @ W + b --------------------
// X bf16 row-major, Wt bf16 = W^T (so B-fragments are contiguous 16B loads).
// MODE 0: fused RoPE epilogue, write bf16 head layout [B,H,SEQ,64]
// MODE 1: write bf16 row-major [M,512]   (V)
// MODE 2: write f32 row-major, * q_mask  (O, into d_out)
template <int MODE, int SEQ>
__global__ __launch_bounds__(256) void proj_gemm(const u16* __restrict__ X,
                                                 const u16* __restrict__ Wt,
                                                 const float* __restrict__ bias,
                                                 void* __restrict__ outp,
                                                 const float2* __restrict__ rope_tab,
                                                 const int* __restrict__ qmask) {
    const int m0 = blockIdx.x * 128, n0 = blockIdx.y * 128;
    const int tid = threadIdx.x;
    const int w = tid >> 6, lane = tid & 63;
    const int lr = lane & 15, lg = lane >> 4;
    const int wm = m0 + (w >> 1) * 64, wn = n0 + (w & 1) * 64;

    f32x4 acc[4][4];
#pragma unroll
    for (int i = 0; i < 4; i++)
#pragma unroll
        for (int j = 0; j < 4; j++) acc[i][j] = f32x4{0.f, 0.f, 0.f, 0.f};

    for (int ks = 0; ks < 16; ks++) {
        const int ko = ks * 32 + lg * 8;
        bf16x8 a[4], bb[4];
#pragma unroll
        for (int mb = 0; mb < 4; mb++) a[mb] = ldbf8(X + (wm + mb * 16 + lr) * E_ + ko);
#pragma unroll
        for (int nb = 0; nb < 4; nb++) bb[nb] = ldbf8(Wt + (wn + nb * 16 + lr) * E_ + ko);
#pragma unroll
        for (int mb = 0; mb < 4; mb++)
#pragma unroll
            for (int nb = 0; nb < 4; nb++)
                acc[mb][nb] = MFMA16(a[mb], bb[nb], acc[mb][nb]);
    }

#pragma unroll
    for (int mb = 0; mb < 4; mb++) {
#pragma unroll
        for (int nb = 0; nb < 4; nb++) {
            const int col = wn + nb * 16 + lr;     // C col = lane&15
            const float bs = bias[col];
#pragma unroll
            for (int r = 0; r < 4; r++) {
                const int row = wm + mb * 16 + lg * 4 + r;  // C row = (lane>>4)*4 + reg
                float v = acc[mb][nb][r] + bs;
                if (MODE == 0) {
                    const int d = col & 63, h = col >> 6;
                    float2 t = rope_tab[row * 16 + (d >> 2)];
                    float other = __shfl_xor(v, 1);  // pair mate: col^1 lives in lane^1
                    float y = (d & 1) ? (other * t.y + v * t.x) : (v * t.x - other * t.y);
                    const int b = row / SEQ, tok = row % SEQ;
                    ((u16*)outp)[((b * H_ + h) * SEQ + tok) * DH_ + d] = f2bf(y);
                } else if (MODE == 1) {
                    ((u16*)outp)[row * E_ + col] = f2bf(v);
                } else {
                    float m = (qmask[row] != 0) ? 1.0f : 0.0f;
                    ((float*)outp)[row * E_ + col] = v * m;
                }
            }
        }
    }
}

// -------------------- V transpose: vt[b,h,d,N] = vlin[b,n,h*64+d] --------------------
__global__ __launch_bounds__(256) void v_transpose(const u16* __restrict__ vlin,
                                                   u16* __restrict__ vt) {
    __shared__ u16 t[64][66];
    int bh = blockIdx.x, n0 = blockIdx.y * 64;
    int b = bh >> 3, h = bh & 7;
    int tid = threadIdx.x;
#pragma unroll
    for (int i = 0; i < 16; i++) {
        int idx = tid + i * 256, r = idx >> 6, c = idx & 63;  // r = n off, c = d
        t[r][c] = vlin[(b * N_ + n0 + r) * E_ + h * DH_ + c];
    }
    __syncthreads();
#pragma unroll
    for (int i = 0; i < 16; i++) {
        int idx = tid + i * 256, r = idx >> 6, c = idx & 63;  // r = d, c = n off
        vt[(bh * DH_ + r) * N_ + n0 + c] = t[c][r];
    }
}

// -------------------- fused attention --------------------
// grid (QT/64, B*H), 256 thr (4 waves x 16 q-rows). Max-free two-pass softmax:
// pass A accumulates per-row sum of exp(score) (masked -> 0, as in ref where
// exp(-1e9 - m) underflows to 0); pass B recomputes scores, writes normalized
// attn (f32, coalesced via LDS), and accumulates ctx = P @ V with bf16 MFMA.
__global__ __launch_bounds__(256) void attn_kernel(const u16* __restrict__ qh,
                                                   const u16* __restrict__ kh,
                                                   const u16* __restrict__ vt,
                                                   const int* __restrict__ kv_mask,
                                                   float* __restrict__ attn_out,
                                                   u16* __restrict__ ctx_out) {
    __shared__ float plds[4][16][68];  // per-wave P tile [16 q][64 kv], padded
    const int qtile = blockIdx.x, bh = blockIdx.y;
    const int b = bh >> 3, h = bh & 7;
    const int tid = threadIdx.x, w = tid >> 6, lane = tid & 63;
    const int lr = lane & 15, lg = lane >> 4;
    const int q0 = qtile * 64 + w * 16;

    const u16* qbase = qh + (bh * QT_ + q0) * DH_;
    const bf16x8 qf0 = ldbf8(qbase + lr * DH_ + lg * 8);
    const bf16x8 qf1 = ldbf8(qbase + lr * DH_ + 32 + lg * 8);
    const u16* kbase = kh + bh * (N_ * DH_);
    const int* mbase = kv_mask + b * N_;

    // ---- pass A: row sums of exp(score) ----
    float lsum[4] = {0.f, 0.f, 0.f, 0.f};
    for (int t = 0; t < 32; t++) {
#pragma unroll
        for (int n = 0; n < 4; n++) {
            const int cb = t * 64 + n * 16;
            bf16x8 k0 = ldbf8(kbase + (cb + lr) * DH_ + lg * 8);
            bf16x8 k1 = ldbf8(kbase + (cb + lr) * DH_ + 32 + lg * 8);
            f32x4 c = f32x4{0.f, 0.f, 0.f, 0.f};
            c = MFMA16(qf0, k0, c);
            c = MFMA16(qf1, k1, c);
            const bool keep = (mbase[cb + lr] != 0);
#pragma unroll
            for (int r = 0; r < 4; r++) lsum[r] += keep ? __expf(c[r] * 0.125f) : 0.f;
        }
    }
    float inv[4];
#pragma unroll
    for (int r = 0; r < 4; r++) {
        float s = lsum[r];
        s += __shfl_xor(s, 1); s += __shfl_xor(s, 2);
        s += __shfl_xor(s, 4); s += __shfl_xor(s, 8);
        inv[r] = (s > 0.f) ? (1.0f / s) : 0.f;  // all-masked row -> attn = 0 (matches ref)
    }

    // ---- pass B: write attn, accumulate ctx ----
    f32x4 pv[4];
#pragma unroll
    for (int i = 0; i < 4; i++) pv[i] = f32x4{0.f, 0.f, 0.f, 0.f};
    float(*P)[68] = plds[w];
    const u16* vbase = vt + bh * (DH_ * N_);
    float* abase = attn_out + ((size_t)(bh * QT_ + q0)) * N_;
    const int srow = lane >> 2, scol = (lane & 3) * 4;

    for (int t = 0; t < 32; t++) {
#pragma unroll
        for (int n = 0; n < 4; n++) {
            const int cb = t * 64 + n * 16;
            bf16x8 k0 = ldbf8(kbase + (cb + lr) * DH_ + lg * 8);
            bf16x8 k1 = ldbf8(kbase + (cb + lr) * DH_ + 32 + lg * 8);
            f32x4 c = f32x4{0.f, 0.f, 0.f, 0.f};
            c = MFMA16(qf0, k0, c);
            c = MFMA16(qf1, k1, c);
            const bool keep = (mbase[cb + lr] != 0);
#pragma unroll
            for (int r = 0; r < 4; r++) {
                float p = keep ? (__expf(c[r] * 0.125f) * inv[r]) : 0.f;
                P[lg * 4 + r][n * 16 + lr] = p;  // per-wave LDS, in-wave ordering only
            }
        }
        // coalesced f32x4 attn stores (4 lanes cover 64B contiguous per row)
#pragma unroll
        for (int i = 0; i < 4; i++) {
            f32x4 vv = *reinterpret_cast<const f32x4*>(&P[srow][i * 16 + scol]);
            *reinterpret_cast<f32x4*>(abase + (size_t)srow * N_ + t * 64 + i * 16 + scol) = vv;
        }
        // PV: ctx[16q,64d] += P[16q,64kv] @ V[64kv,64d]  (A from LDS transpose-read)
#pragma unroll
        for (int ks = 0; ks < 2; ks++) {
            const float* ap = &P[lr][ks * 32 + lg * 8];
            f32x4 a0 = *reinterpret_cast<const f32x4*>(ap);
            f32x4 a1 = *reinterpret_cast<const f32x4*>(ap + 4);
            u16x8 u;
            u[0] = f2bf(a0[0]); u[1] = f2bf(a0[1]); u[2] = f2bf(a0[2]); u[3] = f2bf(a0[3]);
            u[4] = f2bf(a1[0]); u[5] = f2bf(a1[1]); u[6] = f2bf(a1[2]); u[7] = f2bf(a1[3]);
            bf16x8 af = __builtin_bit_cast(bf16x8, u);
#pragma unroll
            for (int nb = 0; nb < 4; nb++) {
                bf16x8 bv = ldbf8(vbase + (nb * 16 + lr) * N_ + t * 64 + ks * 32 + lg * 8);
                pv[nb] = MFMA16(af, bv, pv[nb]);
            }
        }
    }

    // ctx out: [B, QT, H*64] bf16 (feature = h*64+d), feeds O-projection GEMM
#pragma unroll
    for (int nb = 0; nb < 4; nb++) {
#pragma unroll
        for (int r = 0; r < 4; r++) {
            const int row = q0 + lg * 4 + r;
            const int d = nb * 16 + lr;
            ctx_out[((b * QT_ + row) * H_ + h) * DH_ + d] = f2bf(pv[nb][r]);
        }
    }
}

// -------------------- host launch --------------------
extern "C" void kernel_launch(void* const* d_in, const int* in_sizes, int n_in,
                              void* d_out, int out_size, void* d_ws, size_t ws_size,
                              hipStream_t stream) {
    (void)in_sizes; (void)n_in; (void)out_size; (void)ws_size;
    const float* q   = (const float*)d_in[0];
    const float* kv  = (const float*)d_in[1];
    const int* q_mask  = (const int*)d_in[2];
    const int* kv_mask = (const int*)d_in[3];
    const int* q_pos   = (const int*)d_in[4];
    const int* kv_pos  = (const int*)d_in[5];
    const float* Wq = (const float*)d_in[6];  const float* bq = (const float*)d_in[7];
    const float* Wk = (const float*)d_in[8];  const float* bk = (const float*)d_in[9];
    const float* Wv = (const float*)d_in[10]; const float* bv = (const float*)d_in[11];
    const float* Wo = (const float*)d_in[12]; const float* bo = (const float*)d_in[13];
    float* outp = (float*)d_out;

    char* ws = (char*)d_ws;
    size_t off = 0;
    auto carve = [&](size_t bytes) -> void* {
        void* p = ws + off;
        off = (off + bytes + 255) & ~(size_t)255;
        return p;
    };
    u16* qbf   = (u16*)carve((size_t)B_ * QT_ * E_ * 2);
    u16* kvbf  = (u16*)carve((size_t)B_ * N_ * E_ * 2);
    u16* wtq   = (u16*)carve((size_t)E_ * E_ * 2);
    u16* wtk   = (u16*)carve((size_t)E_ * E_ * 2);
    u16* wtv   = (u16*)carve((size_t)E_ * E_ * 2);
    u16* wto   = (u16*)carve((size_t)E_ * E_ * 2);
    u16* qhh   = (u16*)carve((size_t)B_ * H_ * QT_ * DH_ * 2);
    u16* khh   = (u16*)carve((size_t)B_ * H_ * N_ * DH_ * 2);
    u16* vlin  = (u16*)carve((size_t)B_ * N_ * E_ * 2);
    u16* vt    = (u16*)carve((size_t)B_ * H_ * DH_ * N_ * 2);
    u16* ctx   = (u16*)carve((size_t)B_ * QT_ * E_ * 2);
    float2* tq = (float2*)carve((size_t)B_ * QT_ * 16 * sizeof(float2));
    float2* tk = (float2*)carve((size_t)B_ * N_ * 16 * sizeof(float2));

    cvt_f32_bf16<<<(B_ * QT_ * E_ / 4) / 256, 256, 0, stream>>>(q, qbf, B_ * QT_ * E_ / 4);
    cvt_f32_bf16<<<(B_ * N_ * E_ / 4) / 256, 256, 0, stream>>>(kv, kvbf, B_ * N_ * E_ / 4);
    w_transpose<<<dim3(8, 8), 256, 0, stream>>>(Wq, wtq);
    w_transpose<<<dim3(8, 8), 256, 0, stream>>>(Wk, wtk);
    w_transpose<<<dim3(8, 8), 256, 0, stream>>>(Wv, wtv);
    w_transpose<<<dim3(8, 8), 256, 0, stream>>>(Wo, wto);
    rope_table<<<(B_ * QT_ * 16) / 256, 256, 0, stream>>>(q_pos, tq, B_ * QT_);
    rope_table<<<(B_ * N_ * 16) / 256, 256, 0, stream>>>(kv_pos, tk, B_ * N_);

    proj_gemm<0, QT_><<<dim3(B_ * QT_ / 128, 4), 256, 0, stream>>>(qbf, wtq, bq, qhh, tq, nullptr);
    proj_gemm<0, N_><<<dim3(B_ * N_ / 128, 4), 256, 0, stream>>>(kvbf, wtk, bk, khh, tk, nullptr);
    proj_gemm<1, N_><<<dim3(B_ * N_ / 128, 4), 256, 0, stream>>>(kvbf, wtv, bv, vlin, nullptr, nullptr);
    v_transpose<<<dim3(B_ * H_, N_ / 64), 256, 0, stream>>>(vlin, vt);

    attn_kernel<<<dim3(QT_ / 64, B_ * H_), 256, 0, stream>>>(
        qhh, khh, vt, kv_mask, outp + (size_t)B_ * QT_ * E_, ctx);

    proj_gemm<2, QT_><<<dim3(B_ * QT_ / 128, 4), 256, 0, stream>>>(ctx, wto, bo, outp, nullptr, q_mask);
}